// Round 11
// baseline (1663.761 us; speedup 1.0000x reference)
//
#include <hip/hip_runtime.h>
#include <cmath>
#include <cstdint>

namespace {

constexpr int kLevels = 12;      // MAX_LEVELS=12 -> levels >= 12 always masked out
constexpr unsigned kNB = 32768;  // 32^3 Morton buckets
constexpr unsigned kCap = 520;   // float2 entries in per-wave tile arena (4160B)

typedef float f32x4 __attribute__((ext_vector_type(4)));
typedef float f32x4u __attribute__((ext_vector_type(4), aligned(8)));

struct LevelMeta { float scale; unsigned res; unsigned size; unsigned off; };
struct Meta { LevelMeta lv[kLevels]; };

__device__ inline unsigned spread5(unsigned v) {
  v &= 31u;
  v = (v | (v << 8)) & 0x0000100Fu;
  v = (v | (v << 4)) & 0x000010C3u;
  v = (v | (v << 2)) & 0x00001249u;
  return v;
}

__device__ inline unsigned bucket_of(float x, float y, float z) {
  unsigned xi = (unsigned)fminf(fmaxf(x * 32.0f, 0.0f), 31.0f);
  unsigned yi = (unsigned)fminf(fmaxf(y * 32.0f, 0.0f), 31.0f);
  unsigned zi = (unsigned)fminf(fmaxf(z * 32.0f, 0.0f), 31.0f);
  return spread5(xi) | (spread5(yi) << 1) | (spread5(zi) << 2);
}

__device__ inline unsigned rfl(unsigned v) {
  return (unsigned)__builtin_amdgcn_readfirstlane((int)v);
}

}  // namespace

// ---------------- sort prefix ----------------

__global__ __launch_bounds__(256) void k_hist(const float* __restrict__ xyz,
                                              unsigned* __restrict__ counts, int n) {
  const int i = blockIdx.x * blockDim.x + threadIdx.x;
  if (i >= n) return;
  atomicAdd(&counts[bucket_of(xyz[3 * i], xyz[3 * i + 1], xyz[3 * i + 2])], 1u);
}

__global__ __launch_bounds__(1024) void k_scan(const unsigned* __restrict__ counts,
                                               unsigned* __restrict__ cursor) {
  __shared__ unsigned part[1024];
  const int t = threadIdx.x;
  const int base = t * 32;
  unsigned loc[32];
  unsigned run = 0;
#pragma unroll
  for (int j = 0; j < 32; ++j) { loc[j] = run; run += counts[base + j]; }
  part[t] = run;
  __syncthreads();
  for (int off = 1; off < 1024; off <<= 1) {
    unsigned v = (t >= off) ? part[t - off] : 0u;
    __syncthreads();
    part[t] += v;
    __syncthreads();
  }
  const unsigned ebase = part[t] - run;
#pragma unroll
  for (int j = 0; j < 32; ++j) cursor[base + j] = ebase + loc[j];
}

__global__ __launch_bounds__(256) void k_scatter(const float* __restrict__ xyz,
                                                 unsigned* __restrict__ cursor,
                                                 f32x4* __restrict__ sorted, int n) {
  const int i = blockIdx.x * blockDim.x + threadIdx.x;
  if (i >= n) return;
  const float x = xyz[3 * i], y = xyz[3 * i + 1], z = xyz[3 * i + 2];
  const unsigned pos = atomicAdd(&cursor[bucket_of(x, y, z)], 1u);
  f32x4 v;
  v.x = x; v.y = y; v.z = z; v.w = __uint_as_float((unsigned)i);
  sorted[pos] = v;
}

// ---------------- main: R6 structure, occupancy-tuned ----------------
// Per (level,plane) unit: wave-uniform tile -> cooperative coalesced load
// (float4 = 2 cells/lane, 2-deep row pipeline) -> LDS -> per-lane corner
// ds_reads. VGPR forced <= 64 (8 waves/SIMD, the m69 cliff); LDS 16.6KB/block.
// WRAP RULE: the reference wraps EACH cell index independently (idx % size).
// A float4 pair [gi, gi+1] is contiguous mod size EXCEPT when gi == size-1,
// where cell gi+1 must be cell 0 -> patch from tf = tab[0]. (R10's bug.)

__global__ __launch_bounds__(256, 8) void k_main_sorted(
    const f32x4* __restrict__ sorted,
    const float* __restrict__ txy,
    const float* __restrict__ tyz,
    const float* __restrict__ txz,
    const int* __restrict__ step_ptr,
    float* __restrict__ out,
    int n, Meta meta)
{
  __shared__ float2 smem[4][kCap];   // 4160B per wave

  const int tid = threadIdx.x;
  const int wid = tid >> 6;
  const int lane = tid & 63;
  const int g = blockIdx.x * 256 + tid;
  const bool valid = g < n;
  const f32x4 s = sorted[valid ? g : (n - 1)];
  const int rowi = valid ? (int)__float_as_uint(s.w) : -1;

  const int step = *step_ptr;
  int level = step / 1000 + 1;
  level = level > kLevels ? kLevels : level;
  const int active = 2 * level;

  // wave bbox (all lanes hold a valid point; tail lanes clamp to n-1)
  float mnx = s.x, mxx = s.x, mny = s.y, mxy = s.y, mnz = s.z, mxz = s.z;
#pragma unroll
  for (int m = 1; m < 64; m <<= 1) {
    mnx = fminf(mnx, __shfl_xor(mnx, m)); mxx = fmaxf(mxx, __shfl_xor(mxx, m));
    mny = fminf(mny, __shfl_xor(mny, m)); mxy = fmaxf(mxy, __shfl_xor(mxy, m));
    mnz = fminf(mnz, __shfl_xor(mnz, m)); mxz = fmaxf(mxz, __shfl_xor(mxz, m));
  }

  float2* arena = &smem[wid][0];

  float acc[2 * kLevels];
#pragma unroll
  for (int k = 0; k < 2 * kLevels; ++k) acc[k] = 0.0f;

#pragma unroll
  for (int l = 0; l < kLevels; ++l) {
    const LevelMeta lm = meta.lv[l];
#pragma unroll
    for (int p = 0; p < 3; ++p) {
      // direct selection (p compile-time) -> SGPR base + constant offset
      const float2* __restrict__ tab =
          (p == 0 ? reinterpret_cast<const float2*>(txy)
                  : p == 1 ? reinterpret_cast<const float2*>(tyz)
                           : reinterpret_cast<const float2*>(txz)) + lm.off;
      const float c0 = (p == 1) ? s.y : s.x;
      const float c1 = (p == 0) ? s.y : s.z;
      const float b0l = (p == 1) ? mny : mnx, b0h = (p == 1) ? mxy : mxx;
      const float b1l = (p == 0) ? mny : mnz, b1h = (p == 0) ? mxy : mxz;

      const float posx = fmaf(c0, lm.scale, 0.5f);
      const float posy = fmaf(c1, lm.scale, 0.5f);
      const float g0x = floorf(posx), g0y = floorf(posy);
      const float fx = posx - g0x, fy = posy - g0y;
      const unsigned ix = (unsigned)g0x, iy = (unsigned)g0y;

      // wave-uniform tile bounds (fmaf/floor monotone -> hold per-lane)
      const unsigned tx0 = (unsigned)floorf(fmaf(b0l, lm.scale, 0.5f));
      const unsigned tx1 = (unsigned)floorf(fmaf(b0h, lm.scale, 0.5f));
      const unsigned ty0 = (unsigned)floorf(fmaf(b1l, lm.scale, 0.5f));
      const unsigned ty1 = (unsigned)floorf(fmaf(b1h, lm.scale, 0.5f));
      const unsigned X0 = tx0 & ~1u;            // even start for float4 rows
      const unsigned Ceff = tx1 - X0 + 2u;      // cells per row
      const unsigned R = ty1 - ty0 + 2u;        // rows
      // odd stride STRICTLY > Ceff: bank decorrelation + no pair overflow
      const unsigned S = (Ceff & 1u) ? Ceff + 2u : Ceff + 1u;
      const unsigned tiled = (Ceff <= 64u && R * S <= kCap) ? 1u : 0u;
      const unsigned sT = rfl(tiled);

      const float2 tf = *tab;                   // cell 0 (wrap target), uniform

      float2 q00, q01, q10, q11;
      if (sT) {  // scalar branch
        const unsigned sX0 = rfl(X0), sY0 = rfl(ty0);
        const unsigned sC = rfl(Ceff), sR = rfl(R), sS = rfl(S);
        const unsigned scp = (sC + 1u) >> 1;    // float4 units per row
        const unsigned kk = scp > 1u ? 32u - (unsigned)__builtin_clz(scp - 1u) : 0u;
        const unsigned rpi = 64u >> kk;         // rows per instruction
        const unsigned sI = (sR + rpi - 1u) >> (6u - kk);
        const unsigned rr = lane >> kk;
        const unsigned col = (lane & ((1u << kk) - 1u)) * 2u;
        const bool okc = col < sC;

        // row-pair loader with PER-CELL wrap semantics
        auto loadrow = [&](unsigned r) -> f32x4u {
          const unsigned rc = r < sR ? r : sR - 1u;  // junk lanes clamp (in-bounds)
          unsigned gi = (sY0 + rc) * lm.res + sX0 + col;
          if (gi >= lm.size) gi -= lm.size;          // base wrap == ref's %
          f32x4u v = *reinterpret_cast<const f32x4u*>(tab + gi);
          if (gi == lm.size - 1u) { v.z = tf.x; v.w = tf.y; }  // pair straddle
          return v;
        };

        // 2-deep row-group pipeline
        f32x4u v0 = loadrow(rr);
        unsigned d0 = rr * sS + col;
        bool ok0 = okc && (rr < sR);
        for (unsigned t = 1; t < sI; ++t) {
          const unsigned r = t * rpi + rr;
          const f32x4u v1 = loadrow(r);
          if (ok0) {
            arena[d0] = make_float2(v0.x, v0.y);
            arena[d0 + 1] = make_float2(v0.z, v0.w);
          }
          v0 = v1; d0 = r * sS + col; ok0 = okc && (r < sR);
        }
        if (ok0) {
          arena[d0] = make_float2(v0.x, v0.y);
          arena[d0 + 1] = make_float2(v0.z, v0.w);
        }

        const unsigned a = (iy - sY0) * sS + (ix - sX0);
        q00 = arena[a];
        q10 = arena[a + 1];
        q01 = arena[a + sS];
        q11 = arena[a + sS + 1];
      } else {
        // divergent paired-gather fallback (Morton jumps / oversize tiles)
        unsigned i00 = ix + iy * lm.res;        // < size always
        unsigned i01 = i00 + lm.res;            // < 2*size
        if (i01 >= lm.size) i01 -= lm.size;
        const f32x4u r0 = *reinterpret_cast<const f32x4u*>(tab + i00);
        const f32x4u r1 = *reinterpret_cast<const f32x4u*>(tab + i01);
        q00 = make_float2(r0.x, r0.y);
        q10 = (i00 == lm.size - 1u) ? tf : make_float2(r0.z, r0.w);
        q01 = make_float2(r1.x, r1.y);
        q11 = (i01 == lm.size - 1u) ? tf : make_float2(r1.z, r1.w);
      }

      const float w00 = (1.0f - fx) * (1.0f - fy);
      const float w01 = (1.0f - fx) * fy;
      const float w10 = fx * (1.0f - fy);
      const float w11 = fx * fy;
      acc[2 * l + 0] += w00 * q00.x + w01 * q01.x + w10 * q10.x + w11 * q11.x;
      acc[2 * l + 1] += w00 * q00.y + w01 * q01.y + w10 * q10.y + w11 * q11.y;
    }
  }

  // static level mask
#pragma unroll
  for (int k = 0; k < 2 * kLevels; ++k)
    if (k >= active) acc[k] = 0.0f;

  // output staging in the SAME per-wave arena, two half-wave passes.
  // Each pass: 32 lanes write their 8 chunks -> [8][32] float4 (4096B), then
  // the full wave stores 8 complete 128B rows per instruction.
  f32x4* stg = reinterpret_cast<f32x4*>(arena);
  const int half = lane >> 5;
  const int lp = lane & 31;
#pragma unroll
  for (int h = 0; h < 2; ++h) {
    if (half == h) {
#pragma unroll
      for (int c = 0; c < 8; ++c) {
        f32x4 v;
        v.x = c < 6 ? acc[4 * c + 0] : 0.0f;
        v.y = c < 6 ? acc[4 * c + 1] : 0.0f;
        v.z = c < 6 ? acc[4 * c + 2] : 0.0f;
        v.w = c < 6 ? acc[4 * c + 3] : 0.0f;
        stg[c * 32 + lp] = v;
      }
    }
#pragma unroll
    for (int q = 0; q < 4; ++q) {
      const int pl = q * 8 + (lane >> 3);       // point-within-pass [0,32)
      const int c = lane & 7;                   // 16B chunk within row
      const f32x4 v = stg[c * 32 + pl];
      const int r = __shfl(rowi, h * 32 + pl);
      if (r >= 0)
        __builtin_nontemporal_store(v, reinterpret_cast<f32x4*>(out) + (size_t)r * 8 + c);
    }
  }
}

// ---------------- fallback (no-sort) if ws too small ----------------

__global__ __launch_bounds__(256) void k_fused_linear(
    const float* __restrict__ xyz,
    const float* __restrict__ txy,
    const float* __restrict__ tyz,
    const float* __restrict__ txz,
    const int* __restrict__ step_ptr,
    float* __restrict__ out,
    int n, Meta meta)
{
  __shared__ float lds[4 * 2048];
  const int tid = threadIdx.x;
  const int wid = tid >> 6;
  const int lane = tid & 63;
  const int bbase = blockIdx.x * 256;
  const int i = bbase + tid;
  const int pi = i < n ? i : (n - 1);

  const int step = *step_ptr;
  int level = step / 1000 + 1;
  level = level > kLevels ? kLevels : level;
  const int active = 2 * level;

  const float px = xyz[3 * pi], py = xyz[3 * pi + 1], pz = xyz[3 * pi + 2];
  float acc[2 * kLevels];
#pragma unroll
  for (int k = 0; k < 2 * kLevels; ++k) acc[k] = 0.0f;

  auto do_plane = [&](float c0, float c1, const float* __restrict__ tabf) {
    const float2* __restrict__ tab = reinterpret_cast<const float2*>(tabf);
#pragma unroll
    for (int l = 0; l < kLevels; ++l) {
      const LevelMeta lm = meta.lv[l];
      const float2* tb = tab + lm.off;
      const float posx = fmaf(c0, lm.scale, 0.5f);
      const float posy = fmaf(c1, lm.scale, 0.5f);
      const float g0x = floorf(posx), g0y = floorf(posy);
      const float fx = posx - g0x, fy = posy - g0y;
      const unsigned ix = (unsigned)g0x, iy = (unsigned)g0y;
      unsigned i00 = ix + iy * lm.res;
      unsigned i01 = i00 + lm.res;
      if (i01 >= lm.size) i01 -= lm.size;
      const f32x4u r0 = *reinterpret_cast<const f32x4u*>(tb + i00);
      const f32x4u r1 = *reinterpret_cast<const f32x4u*>(tb + i01);
      const float2 tf = *tb;
      const bool w0 = (i00 == lm.size - 1u), w1 = (i01 == lm.size - 1u);
      const float t10x = w0 ? tf.x : r0.z, t10y = w0 ? tf.y : r0.w;
      const float t11x = w1 ? tf.x : r1.z, t11y = w1 ? tf.y : r1.w;
      const float w00 = (1.0f - fx) * (1.0f - fy);
      const float w01 = (1.0f - fx) * fy;
      const float w10 = fx * (1.0f - fy);
      const float w11 = fx * fy;
      acc[2 * l + 0] += w00 * r0.x + w01 * r1.x + w10 * t10x + w11 * t11x;
      acc[2 * l + 1] += w00 * r0.y + w01 * r1.y + w10 * t10y + w11 * t11y;
    }
  };
  do_plane(px, py, txy);
  do_plane(py, pz, tyz);
  do_plane(px, pz, txz);

#pragma unroll
  for (int k = 0; k < 2 * kLevels; ++k)
    if (k >= active) acc[k] = 0.0f;

  float* wlds = lds + wid * 2048;
#pragma unroll
  for (int c = 0; c < 8; ++c) {
    f32x4 v;
    v.x = c < 6 ? acc[4 * c + 0] : 0.0f;
    v.y = c < 6 ? acc[4 * c + 1] : 0.0f;
    v.z = c < 6 ? acc[4 * c + 2] : 0.0f;
    v.w = c < 6 ? acc[4 * c + 3] : 0.0f;
    *reinterpret_cast<f32x4*>(wlds + c * 256 + lane * 4) = v;
  }
  __syncthreads();

  const long long wbase = (long long)bbase + wid * 64;
  f32x4* obase = reinterpret_cast<f32x4*>(out) + wbase * 8;
#pragma unroll
  for (int q = 0; q < 8; ++q) {
    const int p = q * 8 + (lane >> 3);
    const int c = lane & 7;
    const f32x4 v = *reinterpret_cast<const f32x4*>(wlds + c * 256 + p * 4);
    if (wbase + p < n)
      __builtin_nontemporal_store(v, obase + q * 64 + lane);
  }
}

extern "C" void kernel_launch(void* const* d_in, const int* in_sizes, int n_in,
                              void* d_out, int out_size, void* d_ws, size_t ws_size,
                              hipStream_t stream) {
  const float* xyz = (const float*)d_in[0];
  const float* txy = (const float*)d_in[1];
  const float* tyz = (const float*)d_in[2];
  const float* txz = (const float*)d_in[3];
  const int* step  = (const int*)d_in[4];
  float* out = (float*)d_out;
  const int n = in_sizes[0] / 3;

  // Replicate _meta() in double precision (margins >= 0.0128 to every ceil
  // boundary -- far beyond any libm 1-ulp difference vs numpy).
  Meta meta;
  unsigned off = 0;
  const double pls = std::exp2(std::log2(2048.0 / 16.0) / 15.0);
  for (int l = 0; l < 16; ++l) {
    const double scale = 16.0 * std::pow(pls, (double)l) - 1.0;
    const unsigned res = (unsigned)std::ceil(scale) + 1u;
    unsigned long long params = (unsigned long long)res * (unsigned long long)res;
    if (params > (1ull << 19)) params = (1ull << 19);
    params = ((params + 7ull) / 8ull) * 8ull;
    if (l < kLevels) {
      meta.lv[l].scale = (float)scale;
      meta.lv[l].res = res;
      meta.lv[l].size = (unsigned)params;
      meta.lv[l].off = off;
    }
    off += (unsigned)params;
  }

  const dim3 block(256);
  const dim3 grid((unsigned)((n + 255) / 256));

  const size_t sorted_off = 256 * 1024;
  const size_t need = sorted_off + (size_t)n * sizeof(f32x4);

  if (ws_size >= need) {
    unsigned* counts = (unsigned*)d_ws;
    unsigned* cursor = counts + kNB;
    f32x4* sorted = (f32x4*)((char*)d_ws + sorted_off);

    hipMemsetAsync(counts, 0, kNB * sizeof(unsigned), stream);
    hipLaunchKernelGGL(k_hist, grid, block, 0, stream, xyz, counts, n);
    hipLaunchKernelGGL(k_scan, dim3(1), dim3(1024), 0, stream, counts, cursor);
    hipLaunchKernelGGL(k_scatter, grid, block, 0, stream, xyz, cursor, sorted, n);
    hipLaunchKernelGGL(k_main_sorted, grid, block, 0, stream,
                       sorted, txy, tyz, txz, step, out, n, meta);
  } else {
    hipLaunchKernelGGL(k_fused_linear, grid, block, 0, stream,
                       xyz, txy, tyz, txz, step, out, n, meta);
  }
}

// Round 12
// 1305.172 us; speedup vs baseline: 1.2747x; 1.2747x over previous
//
#include <hip/hip_runtime.h>
#include <cmath>
#include <cstdint>

namespace {

constexpr int kLevels = 12;      // MAX_LEVELS=12 -> levels >= 12 always masked out
constexpr unsigned kNB = 32768;  // 32^3 Morton buckets
constexpr unsigned kCap = 520;   // float2 entries in per-wave tile arena (4160B)

typedef float f32x4 __attribute__((ext_vector_type(4)));
typedef float f32x4u __attribute__((ext_vector_type(4), aligned(8)));

struct LevelMeta { float scale; unsigned res; unsigned size; unsigned off; };
struct Meta { LevelMeta lv[kLevels]; };

__device__ inline unsigned spread5(unsigned v) {
  v &= 31u;
  v = (v | (v << 8)) & 0x0000100Fu;
  v = (v | (v << 4)) & 0x000010C3u;
  v = (v | (v << 2)) & 0x00001249u;
  return v;
}

__device__ inline unsigned bucket_of(float x, float y, float z) {
  unsigned xi = (unsigned)fminf(fmaxf(x * 32.0f, 0.0f), 31.0f);
  unsigned yi = (unsigned)fminf(fmaxf(y * 32.0f, 0.0f), 31.0f);
  unsigned zi = (unsigned)fminf(fmaxf(z * 32.0f, 0.0f), 31.0f);
  return spread5(xi) | (spread5(yi) << 1) | (spread5(zi) << 2);
}

__device__ inline unsigned rfl(unsigned v) {
  return (unsigned)__builtin_amdgcn_readfirstlane((int)v);
}

}  // namespace

// ---------------- sort prefix ----------------

__global__ __launch_bounds__(256) void k_hist(const float* __restrict__ xyz,
                                              unsigned* __restrict__ counts, int n) {
  const int i = blockIdx.x * blockDim.x + threadIdx.x;
  if (i >= n) return;
  atomicAdd(&counts[bucket_of(xyz[3 * i], xyz[3 * i + 1], xyz[3 * i + 2])], 1u);
}

__global__ __launch_bounds__(1024) void k_scan(const unsigned* __restrict__ counts,
                                               unsigned* __restrict__ cursor) {
  __shared__ unsigned part[1024];
  const int t = threadIdx.x;
  const int base = t * 32;
  unsigned loc[32];
  unsigned run = 0;
#pragma unroll
  for (int j = 0; j < 32; ++j) { loc[j] = run; run += counts[base + j]; }
  part[t] = run;
  __syncthreads();
  for (int off = 1; off < 1024; off <<= 1) {
    unsigned v = (t >= off) ? part[t - off] : 0u;
    __syncthreads();
    part[t] += v;
    __syncthreads();
  }
  const unsigned ebase = part[t] - run;
#pragma unroll
  for (int j = 0; j < 32; ++j) cursor[base + j] = ebase + loc[j];
}

__global__ __launch_bounds__(256) void k_scatter(const float* __restrict__ xyz,
                                                 unsigned* __restrict__ cursor,
                                                 f32x4* __restrict__ sorted, int n) {
  const int i = blockIdx.x * blockDim.x + threadIdx.x;
  if (i >= n) return;
  const float x = xyz[3 * i], y = xyz[3 * i + 1], z = xyz[3 * i + 2];
  const unsigned pos = atomicAdd(&cursor[bucket_of(x, y, z)], 1u);
  f32x4 v;
  v.x = x; v.y = y; v.z = z; v.w = __uint_as_float((unsigned)i);
  sorted[pos] = v;
}

// ---------------- main: R6 structure, occupancy-tuned (no spill) ----------------
// Per (level,plane) unit: wave-uniform tile -> cooperative coalesced load
// (float4 = 2 cells/lane, 2-deep row pipeline) -> LDS -> per-lane corner
// ds_reads. __launch_bounds__(256,4): VGPR cap 128 -- body fits (~70-90),
// NO SPILL (R11's (256,8) forced 64 -> scratch spill -> 6.1GB HBM junk).
// LDS 16.9KB/block -> 4 blocks/CU via VGPR waves = 16 waves/CU.
// WRAP RULE: reference wraps EACH cell independently; float4 pair [gi, gi+1]
// straddles the wrap iff gi == size-1 -> patch second cell from tab[0].

__global__ __launch_bounds__(256, 4) void k_main_sorted(
    const f32x4* __restrict__ sorted,
    const float* __restrict__ txy,
    const float* __restrict__ tyz,
    const float* __restrict__ txz,
    const int* __restrict__ step_ptr,
    float* __restrict__ out,
    int n, Meta meta)
{
  __shared__ float2 smem[4][kCap];   // 4160B per wave

  const int tid = threadIdx.x;
  const int wid = tid >> 6;
  const int lane = tid & 63;
  const int g = blockIdx.x * 256 + tid;
  const bool valid = g < n;
  const f32x4 s = sorted[valid ? g : (n - 1)];
  const int rowi = valid ? (int)__float_as_uint(s.w) : -1;

  const int step = *step_ptr;
  int level = step / 1000 + 1;
  level = level > kLevels ? kLevels : level;
  const int active = 2 * level;

  // wave bbox (all lanes hold a valid point; tail lanes clamp to n-1)
  float mnx = s.x, mxx = s.x, mny = s.y, mxy = s.y, mnz = s.z, mxz = s.z;
#pragma unroll
  for (int m = 1; m < 64; m <<= 1) {
    mnx = fminf(mnx, __shfl_xor(mnx, m)); mxx = fmaxf(mxx, __shfl_xor(mxx, m));
    mny = fminf(mny, __shfl_xor(mny, m)); mxy = fmaxf(mxy, __shfl_xor(mxy, m));
    mnz = fminf(mnz, __shfl_xor(mnz, m)); mxz = fmaxf(mxz, __shfl_xor(mxz, m));
  }

  float2* arena = &smem[wid][0];

  float acc[2 * kLevels];
#pragma unroll
  for (int k = 0; k < 2 * kLevels; ++k) acc[k] = 0.0f;

#pragma unroll
  for (int l = 0; l < kLevels; ++l) {
    const LevelMeta lm = meta.lv[l];
#pragma unroll
    for (int p = 0; p < 3; ++p) {
      // direct selection (p compile-time) -> SGPR base + constant offset
      const float2* __restrict__ tab =
          (p == 0 ? reinterpret_cast<const float2*>(txy)
                  : p == 1 ? reinterpret_cast<const float2*>(tyz)
                           : reinterpret_cast<const float2*>(txz)) + lm.off;
      const float c0 = (p == 1) ? s.y : s.x;
      const float c1 = (p == 0) ? s.y : s.z;
      const float b0l = (p == 1) ? mny : mnx, b0h = (p == 1) ? mxy : mxx;
      const float b1l = (p == 0) ? mny : mnz, b1h = (p == 0) ? mxy : mxz;

      const float posx = fmaf(c0, lm.scale, 0.5f);
      const float posy = fmaf(c1, lm.scale, 0.5f);
      const float g0x = floorf(posx), g0y = floorf(posy);
      const float fx = posx - g0x, fy = posy - g0y;
      const unsigned ix = (unsigned)g0x, iy = (unsigned)g0y;

      // wave-uniform tile bounds (fmaf/floor monotone -> hold per-lane)
      const unsigned tx0 = (unsigned)floorf(fmaf(b0l, lm.scale, 0.5f));
      const unsigned tx1 = (unsigned)floorf(fmaf(b0h, lm.scale, 0.5f));
      const unsigned ty0 = (unsigned)floorf(fmaf(b1l, lm.scale, 0.5f));
      const unsigned ty1 = (unsigned)floorf(fmaf(b1h, lm.scale, 0.5f));
      const unsigned X0 = tx0 & ~1u;            // even start for float4 rows
      const unsigned Ceff = tx1 - X0 + 2u;      // cells per row
      const unsigned R = ty1 - ty0 + 2u;        // rows
      // odd stride STRICTLY > Ceff: bank decorrelation + no pair overflow
      const unsigned S = (Ceff & 1u) ? Ceff + 2u : Ceff + 1u;
      const unsigned tiled = (Ceff <= 64u && R * S <= kCap) ? 1u : 0u;
      const unsigned sT = rfl(tiled);

      const float2 tf = *tab;                   // cell 0 (wrap target), uniform

      float2 q00, q01, q10, q11;
      if (sT) {  // scalar branch
        const unsigned sX0 = rfl(X0), sY0 = rfl(ty0);
        const unsigned sC = rfl(Ceff), sR = rfl(R), sS = rfl(S);
        const unsigned scp = (sC + 1u) >> 1;    // float4 units per row
        const unsigned kk = scp > 1u ? 32u - (unsigned)__builtin_clz(scp - 1u) : 0u;
        const unsigned rpi = 64u >> kk;         // rows per instruction
        const unsigned sI = (sR + rpi - 1u) >> (6u - kk);
        const unsigned rr = lane >> kk;
        const unsigned col = (lane & ((1u << kk) - 1u)) * 2u;
        const bool okc = col < sC;

        // row-pair loader with PER-CELL wrap semantics
        auto loadrow = [&](unsigned r) -> f32x4u {
          const unsigned rc = r < sR ? r : sR - 1u;  // junk lanes clamp (in-bounds)
          unsigned gi = (sY0 + rc) * lm.res + sX0 + col;
          if (gi >= lm.size) gi -= lm.size;          // base wrap == ref's %
          f32x4u v = *reinterpret_cast<const f32x4u*>(tab + gi);
          if (gi == lm.size - 1u) { v.z = tf.x; v.w = tf.y; }  // pair straddle
          return v;
        };

        // 2-deep row-group pipeline
        f32x4u v0 = loadrow(rr);
        unsigned d0 = rr * sS + col;
        bool ok0 = okc && (rr < sR);
        for (unsigned t = 1; t < sI; ++t) {
          const unsigned r = t * rpi + rr;
          const f32x4u v1 = loadrow(r);
          if (ok0) {
            arena[d0] = make_float2(v0.x, v0.y);
            arena[d0 + 1] = make_float2(v0.z, v0.w);
          }
          v0 = v1; d0 = r * sS + col; ok0 = okc && (r < sR);
        }
        if (ok0) {
          arena[d0] = make_float2(v0.x, v0.y);
          arena[d0 + 1] = make_float2(v0.z, v0.w);
        }

        const unsigned a = (iy - sY0) * sS + (ix - sX0);
        q00 = arena[a];
        q10 = arena[a + 1];
        q01 = arena[a + sS];
        q11 = arena[a + sS + 1];
      } else {
        // divergent paired-gather fallback (Morton jumps / oversize tiles)
        unsigned i00 = ix + iy * lm.res;        // < size always
        unsigned i01 = i00 + lm.res;            // < 2*size
        if (i01 >= lm.size) i01 -= lm.size;
        const f32x4u r0 = *reinterpret_cast<const f32x4u*>(tab + i00);
        const f32x4u r1 = *reinterpret_cast<const f32x4u*>(tab + i01);
        q00 = make_float2(r0.x, r0.y);
        q10 = (i00 == lm.size - 1u) ? tf : make_float2(r0.z, r0.w);
        q01 = make_float2(r1.x, r1.y);
        q11 = (i01 == lm.size - 1u) ? tf : make_float2(r1.z, r1.w);
      }

      const float w00 = (1.0f - fx) * (1.0f - fy);
      const float w01 = (1.0f - fx) * fy;
      const float w10 = fx * (1.0f - fy);
      const float w11 = fx * fy;
      acc[2 * l + 0] += w00 * q00.x + w01 * q01.x + w10 * q10.x + w11 * q11.x;
      acc[2 * l + 1] += w00 * q00.y + w01 * q01.y + w10 * q10.y + w11 * q11.y;
    }
  }

  // static level mask
#pragma unroll
  for (int k = 0; k < 2 * kLevels; ++k)
    if (k >= active) acc[k] = 0.0f;

  // output staging in the SAME per-wave arena, two half-wave passes.
  // Each pass: 32 lanes write their 8 chunks -> [8][32] float4 (4096B), then
  // the full wave stores 8 complete 128B rows per instruction.
  f32x4* stg = reinterpret_cast<f32x4*>(arena);
  const int half = lane >> 5;
  const int lp = lane & 31;
#pragma unroll
  for (int h = 0; h < 2; ++h) {
    if (half == h) {
#pragma unroll
      for (int c = 0; c < 8; ++c) {
        f32x4 v;
        v.x = c < 6 ? acc[4 * c + 0] : 0.0f;
        v.y = c < 6 ? acc[4 * c + 1] : 0.0f;
        v.z = c < 6 ? acc[4 * c + 2] : 0.0f;
        v.w = c < 6 ? acc[4 * c + 3] : 0.0f;
        stg[c * 32 + lp] = v;
      }
    }
#pragma unroll
    for (int q = 0; q < 4; ++q) {
      const int pl = q * 8 + (lane >> 3);       // point-within-pass [0,32)
      const int c = lane & 7;                   // 16B chunk within row
      const f32x4 v = stg[c * 32 + pl];
      const int r = __shfl(rowi, h * 32 + pl);
      if (r >= 0)
        __builtin_nontemporal_store(v, reinterpret_cast<f32x4*>(out) + (size_t)r * 8 + c);
    }
  }
}

// ---------------- fallback (no-sort) if ws too small ----------------

__global__ __launch_bounds__(256) void k_fused_linear(
    const float* __restrict__ xyz,
    const float* __restrict__ txy,
    const float* __restrict__ tyz,
    const float* __restrict__ txz,
    const int* __restrict__ step_ptr,
    float* __restrict__ out,
    int n, Meta meta)
{
  __shared__ float lds[4 * 2048];
  const int tid = threadIdx.x;
  const int wid = tid >> 6;
  const int lane = tid & 63;
  const int bbase = blockIdx.x * 256;
  const int i = bbase + tid;
  const int pi = i < n ? i : (n - 1);

  const int step = *step_ptr;
  int level = step / 1000 + 1;
  level = level > kLevels ? kLevels : level;
  const int active = 2 * level;

  const float px = xyz[3 * pi], py = xyz[3 * pi + 1], pz = xyz[3 * pi + 2];
  float acc[2 * kLevels];
#pragma unroll
  for (int k = 0; k < 2 * kLevels; ++k) acc[k] = 0.0f;

  auto do_plane = [&](float c0, float c1, const float* __restrict__ tabf) {
    const float2* __restrict__ tab = reinterpret_cast<const float2*>(tabf);
#pragma unroll
    for (int l = 0; l < kLevels; ++l) {
      const LevelMeta lm = meta.lv[l];
      const float2* tb = tab + lm.off;
      const float posx = fmaf(c0, lm.scale, 0.5f);
      const float posy = fmaf(c1, lm.scale, 0.5f);
      const float g0x = floorf(posx), g0y = floorf(posy);
      const float fx = posx - g0x, fy = posy - g0y;
      const unsigned ix = (unsigned)g0x, iy = (unsigned)g0y;
      unsigned i00 = ix + iy * lm.res;
      unsigned i01 = i00 + lm.res;
      if (i01 >= lm.size) i01 -= lm.size;
      const f32x4u r0 = *reinterpret_cast<const f32x4u*>(tb + i00);
      const f32x4u r1 = *reinterpret_cast<const f32x4u*>(tb + i01);
      const float2 tf = *tb;
      const bool w0 = (i00 == lm.size - 1u), w1 = (i01 == lm.size - 1u);
      const float t10x = w0 ? tf.x : r0.z, t10y = w0 ? tf.y : r0.w;
      const float t11x = w1 ? tf.x : r1.z, t11y = w1 ? tf.y : r1.w;
      const float w00 = (1.0f - fx) * (1.0f - fy);
      const float w01 = (1.0f - fx) * fy;
      const float w10 = fx * (1.0f - fy);
      const float w11 = fx * fy;
      acc[2 * l + 0] += w00 * r0.x + w01 * r1.x + w10 * t10x + w11 * t11x;
      acc[2 * l + 1] += w00 * r0.y + w01 * r1.y + w10 * t10y + w11 * t11y;
    }
  };
  do_plane(px, py, txy);
  do_plane(py, pz, tyz);
  do_plane(px, pz, txz);

#pragma unroll
  for (int k = 0; k < 2 * kLevels; ++k)
    if (k >= active) acc[k] = 0.0f;

  float* wlds = lds + wid * 2048;
#pragma unroll
  for (int c = 0; c < 8; ++c) {
    f32x4 v;
    v.x = c < 6 ? acc[4 * c + 0] : 0.0f;
    v.y = c < 6 ? acc[4 * c + 1] : 0.0f;
    v.z = c < 6 ? acc[4 * c + 2] : 0.0f;
    v.w = c < 6 ? acc[4 * c + 3] : 0.0f;
    *reinterpret_cast<f32x4*>(wlds + c * 256 + lane * 4) = v;
  }
  __syncthreads();

  const long long wbase = (long long)bbase + wid * 64;
  f32x4* obase = reinterpret_cast<f32x4*>(out) + wbase * 8;
#pragma unroll
  for (int q = 0; q < 8; ++q) {
    const int p = q * 8 + (lane >> 3);
    const int c = lane & 7;
    const f32x4 v = *reinterpret_cast<const f32x4*>(wlds + c * 256 + p * 4);
    if (wbase + p < n)
      __builtin_nontemporal_store(v, obase + q * 64 + lane);
  }
}

extern "C" void kernel_launch(void* const* d_in, const int* in_sizes, int n_in,
                              void* d_out, int out_size, void* d_ws, size_t ws_size,
                              hipStream_t stream) {
  const float* xyz = (const float*)d_in[0];
  const float* txy = (const float*)d_in[1];
  const float* tyz = (const float*)d_in[2];
  const float* txz = (const float*)d_in[3];
  const int* step  = (const int*)d_in[4];
  float* out = (float*)d_out;
  const int n = in_sizes[0] / 3;

  // Replicate _meta() in double precision (margins >= 0.0128 to every ceil
  // boundary -- far beyond any libm 1-ulp difference vs numpy).
  Meta meta;
  unsigned off = 0;
  const double pls = std::exp2(std::log2(2048.0 / 16.0) / 15.0);
  for (int l = 0; l < 16; ++l) {
    const double scale = 16.0 * std::pow(pls, (double)l) - 1.0;
    const unsigned res = (unsigned)std::ceil(scale) + 1u;
    unsigned long long params = (unsigned long long)res * (unsigned long long)res;
    if (params > (1ull << 19)) params = (1ull << 19);
    params = ((params + 7ull) / 8ull) * 8ull;
    if (l < kLevels) {
      meta.lv[l].scale = (float)scale;
      meta.lv[l].res = res;
      meta.lv[l].size = (unsigned)params;
      meta.lv[l].off = off;
    }
    off += (unsigned)params;
  }

  const dim3 block(256);
  const dim3 grid((unsigned)((n + 255) / 256));

  const size_t sorted_off = 256 * 1024;
  const size_t need = sorted_off + (size_t)n * sizeof(f32x4);

  if (ws_size >= need) {
    unsigned* counts = (unsigned*)d_ws;
    unsigned* cursor = counts + kNB;
    f32x4* sorted = (f32x4*)((char*)d_ws + sorted_off);

    hipMemsetAsync(counts, 0, kNB * sizeof(unsigned), stream);
    hipLaunchKernelGGL(k_hist, grid, block, 0, stream, xyz, counts, n);
    hipLaunchKernelGGL(k_scan, dim3(1), dim3(1024), 0, stream, counts, cursor);
    hipLaunchKernelGGL(k_scatter, grid, block, 0, stream, xyz, cursor, sorted, n);
    hipLaunchKernelGGL(k_main_sorted, grid, block, 0, stream,
                       sorted, txy, tyz, txz, step, out, n, meta);
  } else {
    hipLaunchKernelGGL(k_fused_linear, grid, block, 0, stream,
                       xyz, txy, tyz, txz, step, out, n, meta);
  }
}

// Round 13
// 559.052 us; speedup vs baseline: 2.9760x; 2.3346x over previous
//
#include <hip/hip_runtime.h>
#include <cmath>
#include <cstdint>

namespace {

constexpr int kLevels = 12;      // MAX_LEVELS=12 -> levels >= 12 always masked out
constexpr int kBatch = 4;        // levels per MLP batch: 4 keeps VGPR < 128 (16 waves/CU)
constexpr unsigned kNB = 32768;  // 32^3 Morton buckets

typedef float f32x4 __attribute__((ext_vector_type(4)));
typedef float f32x4u __attribute__((ext_vector_type(4), aligned(8)));

struct LevelMeta { float scale; unsigned res; unsigned size; unsigned off; };
struct Meta { LevelMeta lv[kLevels]; };

__device__ inline unsigned spread5(unsigned v) {
  v &= 31u;
  v = (v | (v << 8)) & 0x0000100Fu;
  v = (v | (v << 4)) & 0x000010C3u;
  v = (v | (v << 2)) & 0x00001249u;
  return v;
}

__device__ inline unsigned bucket_of(float x, float y, float z) {
  unsigned xi = (unsigned)fminf(fmaxf(x * 32.0f, 0.0f), 31.0f);
  unsigned yi = (unsigned)fminf(fmaxf(y * 32.0f, 0.0f), 31.0f);
  unsigned zi = (unsigned)fminf(fmaxf(z * 32.0f, 0.0f), 31.0f);
  return spread5(xi) | (spread5(yi) << 1) | (spread5(zi) << 2);
}

// Bilinear-gather core over the 3 planes, batched for MLP (kBatch levels of
// paired 16B gathers in flight at once). Wrap semantics == reference's %size:
// i00 never wraps; i01 one conditional subtract; i10/i11 wrap to cell 0 iff
// their base is size-1 (patched from tab[0]).
__device__ inline void gather_planes(float px, float py, float pz,
                                     const float* __restrict__ txy,
                                     const float* __restrict__ tyz,
                                     const float* __restrict__ txz,
                                     const Meta& meta, float* acc) {
  auto do_plane = [&](float c0, float c1, const float* __restrict__ tabf) {
    const float2* __restrict__ tab = reinterpret_cast<const float2*>(tabf);
#pragma unroll
    for (int h = 0; h < kLevels / kBatch; ++h) {
      f32x4 r0[kBatch], r1[kBatch];
      float fxs[kBatch], fys[kBatch];
      unsigned wrap0 = 0, wrap1 = 0;

#pragma unroll
      for (int j = 0; j < kBatch; ++j) {
        const int l = h * kBatch + j;
        const LevelMeta lm = meta.lv[l];
        const float2* tb = tab + lm.off;

        const float posx = fmaf(c0, lm.scale, 0.5f);
        const float posy = fmaf(c1, lm.scale, 0.5f);
        const float g0x = floorf(posx);
        const float g0y = floorf(posy);
        fxs[j] = posx - g0x;
        fys[j] = posy - g0y;
        const unsigned ix = (unsigned)g0x;
        const unsigned iy = (unsigned)g0y;

        unsigned i00 = ix + iy * lm.res;        // < size always
        unsigned i01 = i00 + lm.res;            // < 2*size
        if (i01 >= lm.size) i01 -= lm.size;
        wrap0 |= (i00 == lm.size - 1u) ? (1u << j) : 0u;
        wrap1 |= (i01 == lm.size - 1u) ? (1u << j) : 0u;
        // paired 16B gathers; reading one float2 past the level region is
        // in-bounds (next level's data follows; value replaced when wrapped)
        r0[j] = *reinterpret_cast<const f32x4u*>(tb + i00);
        r1[j] = *reinterpret_cast<const f32x4u*>(tb + i01);
      }

#pragma unroll
      for (int j = 0; j < kBatch; ++j) {
        const int l = h * kBatch + j;
        const float2* tb = tab + meta.lv[l].off;
        const float2 tf = *tb;  // wrap target is always cell 0

        const float fx = fxs[j];
        const float fy = fys[j];
        const bool w0 = (wrap0 >> j) & 1u;
        const bool w1 = (wrap1 >> j) & 1u;
        const float t10x = w0 ? tf.x : r0[j].z;
        const float t10y = w0 ? tf.y : r0[j].w;
        const float t11x = w1 ? tf.x : r1[j].z;
        const float t11y = w1 ? tf.y : r1[j].w;

        const float w00 = (1.0f - fx) * (1.0f - fy);
        const float w01 = (1.0f - fx) * fy;
        const float w10 = fx * (1.0f - fy);
        const float w11 = fx * fy;

        acc[2 * l + 0] += w00 * r0[j].x + w01 * r1[j].x + w10 * t10x + w11 * t11x;
        acc[2 * l + 1] += w00 * r0[j].y + w01 * r1[j].y + w10 * t10y + w11 * t11y;
      }
    }
  };
  do_plane(px, py, txy);
  do_plane(py, pz, tyz);
  do_plane(px, pz, txz);
}

}  // namespace

// ---------------- sort prefix ----------------

__global__ __launch_bounds__(256) void k_hist(const float* __restrict__ xyz,
                                              unsigned* __restrict__ counts, int n) {
  const int i = blockIdx.x * blockDim.x + threadIdx.x;
  if (i >= n) return;
  atomicAdd(&counts[bucket_of(xyz[3 * i], xyz[3 * i + 1], xyz[3 * i + 2])], 1u);
}

__global__ __launch_bounds__(1024) void k_scan(const unsigned* __restrict__ counts,
                                               unsigned* __restrict__ cursor) {
  __shared__ unsigned part[1024];
  const int t = threadIdx.x;
  const int base = t * 32;
  unsigned loc[32];
  unsigned run = 0;
#pragma unroll
  for (int j = 0; j < 32; ++j) { loc[j] = run; run += counts[base + j]; }
  part[t] = run;
  __syncthreads();
  for (int off = 1; off < 1024; off <<= 1) {
    unsigned v = (t >= off) ? part[t - off] : 0u;
    __syncthreads();
    part[t] += v;
    __syncthreads();
  }
  const unsigned ebase = part[t] - run;
#pragma unroll
  for (int j = 0; j < 32; ++j) cursor[base + j] = ebase + loc[j];
}

__global__ __launch_bounds__(256) void k_scatter(const float* __restrict__ xyz,
                                                 unsigned* __restrict__ cursor,
                                                 f32x4* __restrict__ sorted, int n) {
  const int i = blockIdx.x * blockDim.x + threadIdx.x;
  if (i >= n) return;
  const float x = xyz[3 * i], y = xyz[3 * i + 1], z = xyz[3 * i + 2];
  const unsigned pos = atomicAdd(&cursor[bucket_of(x, y, z)], 1u);
  f32x4 v;
  v.x = x; v.y = y; v.z = z; v.w = __uint_as_float((unsigned)i);
  sorted[pos] = v;
}

// ---------------- main: sorted divergent gathers, kBatch=4 MLP ----------------
// Proven R4 structure (343us @ 8 waves/CU, VGPR 144 w/ kBatch=6). kBatch=4
// drops in-flight load state by 24 VGPR -> target <=128 -> 16 waves/CU.
// NO min-waves launch-bounds hint (R11/R12: it triggers allocator spill).

__global__ __launch_bounds__(256) void k_main_sorted(
    const f32x4* __restrict__ sorted,
    const float* __restrict__ txy,
    const float* __restrict__ tyz,
    const float* __restrict__ txz,
    const int* __restrict__ step_ptr,
    float* __restrict__ out,
    int n, Meta meta)
{
  // [4 waves][8 chunks][260 floats] staging (+4 pad per chunk row) + idxs
  __shared__ float lds[4 * 2080];
  __shared__ unsigned idxs[256];

  const int tid = threadIdx.x;
  const int wid = tid >> 6;
  const int lane = tid & 63;
  const int g = blockIdx.x * 256 + tid;
  const bool valid = g < n;
  const f32x4 s = sorted[valid ? g : (n - 1)];
  const unsigned row = valid ? __float_as_uint(s.w) : 0xFFFFFFFFu;

  const int step = *step_ptr;
  int level = step / 1000 + 1;
  level = level > kLevels ? kLevels : level;
  const int active = 2 * level;

  float acc[2 * kLevels];
#pragma unroll
  for (int k = 0; k < 2 * kLevels; ++k) acc[k] = 0.0f;

  gather_planes(s.x, s.y, s.z, txy, tyz, txz, meta, acc);

#pragma unroll
  for (int k = 0; k < 2 * kLevels; ++k)
    if (k >= active) acc[k] = 0.0f;

  // stage 8KB/wave in LDS, then each store instruction covers 8 whole
  // 128B output rows (one line each) -> no write amplification
  float* wlds = lds + wid * 2080;
#pragma unroll
  for (int c = 0; c < 8; ++c) {
    f32x4 v;
    v.x = c < 6 ? acc[4 * c + 0] : 0.0f;
    v.y = c < 6 ? acc[4 * c + 1] : 0.0f;
    v.z = c < 6 ? acc[4 * c + 2] : 0.0f;
    v.w = c < 6 ? acc[4 * c + 3] : 0.0f;
    *reinterpret_cast<f32x4*>(wlds + c * 260 + lane * 4) = v;
  }
  idxs[tid] = row;
  __syncthreads();

#pragma unroll
  for (int q = 0; q < 8; ++q) {
    const int p = q * 8 + (lane >> 3);   // point within wave
    const int c = lane & 7;              // 16B chunk within row
    const unsigned r = idxs[wid * 64 + p];
    const f32x4 v = *reinterpret_cast<const f32x4*>(wlds + c * 260 + p * 4);
    if (r != 0xFFFFFFFFu)
      __builtin_nontemporal_store(v, reinterpret_cast<f32x4*>(out) + (size_t)r * 8 + c);
  }
}

// ---------------- fallback (no-sort) if ws too small ----------------

__global__ __launch_bounds__(256) void k_fused_linear(
    const float* __restrict__ xyz,
    const float* __restrict__ txy,
    const float* __restrict__ tyz,
    const float* __restrict__ txz,
    const int* __restrict__ step_ptr,
    float* __restrict__ out,
    int n, Meta meta)
{
  __shared__ float lds[4 * 2048];
  const int tid = threadIdx.x;
  const int wid = tid >> 6;
  const int lane = tid & 63;
  const int bbase = blockIdx.x * 256;
  const int i = bbase + tid;
  const int pi = i < n ? i : (n - 1);

  const int step = *step_ptr;
  int level = step / 1000 + 1;
  level = level > kLevels ? kLevels : level;
  const int active = 2 * level;

  float acc[2 * kLevels];
#pragma unroll
  for (int k = 0; k < 2 * kLevels; ++k) acc[k] = 0.0f;

  gather_planes(xyz[3 * pi], xyz[3 * pi + 1], xyz[3 * pi + 2],
                txy, tyz, txz, meta, acc);

#pragma unroll
  for (int k = 0; k < 2 * kLevels; ++k)
    if (k >= active) acc[k] = 0.0f;

  float* wlds = lds + wid * 2048;
#pragma unroll
  for (int c = 0; c < 8; ++c) {
    f32x4 v;
    v.x = c < 6 ? acc[4 * c + 0] : 0.0f;
    v.y = c < 6 ? acc[4 * c + 1] : 0.0f;
    v.z = c < 6 ? acc[4 * c + 2] : 0.0f;
    v.w = c < 6 ? acc[4 * c + 3] : 0.0f;
    *reinterpret_cast<f32x4*>(wlds + c * 256 + lane * 4) = v;
  }
  __syncthreads();

  const long long wbase = (long long)bbase + wid * 64;
  f32x4* obase = reinterpret_cast<f32x4*>(out) + wbase * 8;
#pragma unroll
  for (int q = 0; q < 8; ++q) {
    const int p = q * 8 + (lane >> 3);
    const int c = lane & 7;
    const f32x4 v = *reinterpret_cast<const f32x4*>(wlds + c * 256 + p * 4);
    if (wbase + p < n)
      __builtin_nontemporal_store(v, obase + q * 64 + lane);
  }
}

extern "C" void kernel_launch(void* const* d_in, const int* in_sizes, int n_in,
                              void* d_out, int out_size, void* d_ws, size_t ws_size,
                              hipStream_t stream) {
  const float* xyz = (const float*)d_in[0];
  const float* txy = (const float*)d_in[1];
  const float* tyz = (const float*)d_in[2];
  const float* txz = (const float*)d_in[3];
  const int* step  = (const int*)d_in[4];
  float* out = (float*)d_out;
  const int n = in_sizes[0] / 3;

  // Replicate _meta() in double precision (margins >= 0.0128 to every ceil
  // boundary -- far beyond any libm 1-ulp difference vs numpy).
  Meta meta;
  unsigned off = 0;
  const double pls = std::exp2(std::log2(2048.0 / 16.0) / 15.0);
  for (int l = 0; l < 16; ++l) {
    const double scale = 16.0 * std::pow(pls, (double)l) - 1.0;
    const unsigned res = (unsigned)std::ceil(scale) + 1u;
    unsigned long long params = (unsigned long long)res * (unsigned long long)res;
    if (params > (1ull << 19)) params = (1ull << 19);
    params = ((params + 7ull) / 8ull) * 8ull;
    if (l < kLevels) {
      meta.lv[l].scale = (float)scale;
      meta.lv[l].res = res;
      meta.lv[l].size = (unsigned)params;
      meta.lv[l].off = off;
    }
    off += (unsigned)params;
  }

  const dim3 block(256);
  const dim3 grid((unsigned)((n + 255) / 256));

  const size_t sorted_off = 256 * 1024;
  const size_t need = sorted_off + (size_t)n * sizeof(f32x4);

  if (ws_size >= need) {
    unsigned* counts = (unsigned*)d_ws;
    unsigned* cursor = counts + kNB;
    f32x4* sorted = (f32x4*)((char*)d_ws + sorted_off);

    hipMemsetAsync(counts, 0, kNB * sizeof(unsigned), stream);
    hipLaunchKernelGGL(k_hist, grid, block, 0, stream, xyz, counts, n);
    hipLaunchKernelGGL(k_scan, dim3(1), dim3(1024), 0, stream, counts, cursor);
    hipLaunchKernelGGL(k_scatter, grid, block, 0, stream, xyz, cursor, sorted, n);
    hipLaunchKernelGGL(k_main_sorted, grid, block, 0, stream,
                       sorted, txy, tyz, txz, step, out, n, meta);
  } else {
    hipLaunchKernelGGL(k_fused_linear, grid, block, 0, stream,
                       xyz, txy, tyz, txz, step, out, n, meta);
  }
}